// Round 6
// baseline (107.234 us; speedup 1.0000x reference)
//
#include <hip/hip_runtime.h>
#include <cstddef>

// InfoNCE loss, B=8192, D=128.
// prep: normalize + bf16 cast + (label u, conf-sign w) + raw self-dot
// sim:  TRIANGLE-symmetric bf16 MFMA E.E^T (2080 of 4096 tile-pairs):
//       one 128x128 tile-pair per block; off-diag blocks accumulate BOTH
//       row-side and col-side masked sums (sim is exactly symmetric since
//       both MFMA operands come from the same bf16 array; TEMP_SCALE is
//       applied post-MFMA inside the exp2 fma). Validity w_i*w_j>0 folded
//       into the exp2 argument. 37 KB LDS -> 4 blocks/CU; reg demand ~110
//       stays under the ~budget/2 = 128 the allocator picks (r2-r5 lesson).
// fin:  per-row loss from (tot, dif), mean over valid rows

#define DDIM 128
#define TEMP_SCALE 14.4269504088896340736f  // (1/0.1) * log2(e)

typedef short s8bf __attribute__((ext_vector_type(8)));   // 8 bf16 (4 VGPRs)
typedef float f32x4 __attribute__((ext_vector_type(4)));

typedef __attribute__((address_space(1))) void gas_void;
typedef __attribute__((address_space(3))) void las_void;

__device__ __forceinline__ void gload_lds16(const void* g, void* l) {
    __builtin_amdgcn_global_load_lds((gas_void*)g, (las_void*)l, 16, 0, 0);
}

__device__ __forceinline__ unsigned short f2bf(float f) {
    unsigned int u = __float_as_uint(f);
    u += 0x7fffu + ((u >> 16) & 1u);
    return (unsigned short)(u >> 16);
}
__device__ __forceinline__ float bf2f(unsigned short h) {
    return __uint_as_float(((unsigned int)h) << 16);
}

// ---------------- prep: one wave per row ----------------
__global__ __launch_bounds__(256) void prep_kernel(
    const float* __restrict__ emb, const int* __restrict__ labels,
    const float* __restrict__ conf,
    short* __restrict__ Eb,    // bf16(e) — the ONLY embedding array (symmetric)
    float2* __restrict__ uc,   // (label +-1, conf-sign w)
    float* __restrict__ sd,    // raw self-dot of bf16(e) (unscaled)
    float* __restrict__ tot, float* __restrict__ dif, int B)
{
    int wave = threadIdx.x >> 6;
    int lane = threadIdx.x & 63;
    int row  = blockIdx.x * 4 + wave;
    if (row >= B) return;

    float2 x = ((const float2*)(emb + (size_t)row * DDIM))[lane];
    float ss = x.x * x.x + x.y * x.y;
    #pragma unroll
    for (int m = 32; m; m >>= 1) ss += __shfl_xor(ss, m);
    float inv = 1.0f / fmaxf(sqrtf(ss), 1e-12f);

    unsigned short eb0 = f2bf(x.x * inv), eb1 = f2bf(x.y * inv);
    *(ushort2*)(Eb + (size_t)row * DDIM + lane * 2) = make_ushort2(eb0, eb1);

    float b0 = bf2f(eb0), b1 = bf2f(eb1);
    float p = b0 * b0 + b1 * b1;
    #pragma unroll
    for (int m = 32; m; m >>= 1) p += __shfl_xor(p, m);

    if (lane == 0) {
        sd[row] = p;
        float l = labels[row] ? 1.0f : -1.0f;
        float c = conf[row];
        float w = (c > 0.0f) ? 1.0f : ((c < 0.0f) ? -1.0f : 0.0f);
        uc[row] = make_float2(l, w);
        tot[row] = 0.0f;
        dif[row] = 0.0f;
    }
}

// ---------------- sim ----------------
// One 128x128 tile-pair (bi<=bj) per 256-thr block (4 waves x 2 row-tiles).
// Cols of tile bj staged via swizzled gload_lds (r5-verified involution:
// LDS[L] = G[L ^ ((L>>8&7)<<4)]; reads apply the same XOR).
// Per element: e = exp2(fma(acc, S, bias)), bias = fma(w_r*w_c, 5e29, -5e29)
// (w-prod 1 -> 0, 0 -> -5e29, -1 -> -1e30: invalid pairs give e = 0).
// Row-side: rtot += e, rdif += u_c*e.  Col-side (off-diag only, by symmetry):
// ctot += e, cdif += u_r*e, quad-reduced, per-wave LDS slot, combined at end.
#define MFMA16(A, Bf, C) __builtin_amdgcn_mfma_f32_16x16x32_bf16((A), (Bf), (C), 0, 0, 0)

__global__ __launch_bounds__(256, 2) void sim_kernel(
    const short* __restrict__ Eb, const float2* __restrict__ uc,
    float* __restrict__ tot, float* __restrict__ dif, int NT)
{
    __shared__ short tile[128 * 128];      // 32 KB, swizzled, linear for gload_lds
    __shared__ float2 ucc[128];            // col (u, w)
    __shared__ float2 colbuf[4][128];      // per-wave col-side partials (4 KB)

    // triangle decode: bi <= bj, C(i) = i*(M-i)/2, M = 2*NT+1
    const int M = 2 * NT + 1;
    int bid = (int)blockIdx.x;
    int bi = (int)((M - sqrtf((float)(M * M - 8 * bid))) * 0.5f);
    while (bi > 0 && bi * (M - bi) / 2 > bid) --bi;
    while ((bi + 1) * (M - bi - 1) / 2 <= bid) ++bi;
    const int bj = bi + (bid - bi * (M - bi) / 2);
    const bool offdiag = (bi != bj);

    const int lane = threadIdx.x & 63;
    const int wave = threadIdx.x >> 6;
    const int l16  = lane & 15;
    const int quad = lane >> 4;
    const int rowBase = bi * 128 + wave * 32;   // 2 row-tiles
    const int colBase = bj * 128;

    // ---- stage col tile via DMA (inverse-swizzled source, linear LDS) ----
    {
        const char* gb = (const char*)Eb + (size_t)colBase * 256;
        #pragma unroll
        for (int i = 0; i < 8; ++i) {
            int L  = i * 4096 + wave * 1024 + lane * 16;
            int Ls = L ^ (((L >> 8) & 7) << 4);
            gload_lds16(gb + Ls, (char*)tile + L);
        }
    }
    if (threadIdx.x < 128) ucc[threadIdx.x] = uc[colBase + threadIdx.x];

    // A fragments from the SAME array (exact symmetry): A[m=l16][k=quad*8+j]
    s8bf a[2][4];
    #pragma unroll
    for (int t = 0; t < 2; ++t)
        #pragma unroll
        for (int k = 0; k < 4; ++k)
            a[t][k] = *(const s8bf*)(Eb + (size_t)(rowBase + t * 16 + l16) * DDIM + k * 32 + quad * 8);

    // row characters; C/D layout: col = lane&15, row = quad*4 + reg
    float ur[2][4], wr[2][4];
    #pragma unroll
    for (int t = 0; t < 2; ++t)
        #pragma unroll
        for (int r = 0; r < 4; ++r) {
            float2 v = uc[rowBase + t * 16 + quad * 4 + r];
            ur[t][r] = v.x; wr[t][r] = v.y;
        }

    float rtot[2][4], rdif[2][4];
    #pragma unroll
    for (int t = 0; t < 2; ++t)
        #pragma unroll
        for (int r = 0; r < 4; ++r) { rtot[t][r] = 0.0f; rdif[t][r] = 0.0f; }

    __syncthreads();   // drains DMA (vmcnt 0); ucc visible

    const int swz = (l16 & 7) << 4;
    #pragma unroll
    for (int ct = 0; ct < 8; ++ct) {
        const char* tb = (const char*)tile + (ct * 16 + l16) * 256;
        s8bf b0 = *(const s8bf*)(tb + ((  0 + quad * 16) ^ swz));
        s8bf b1 = *(const s8bf*)(tb + (( 64 + quad * 16) ^ swz));
        s8bf b2 = *(const s8bf*)(tb + ((128 + quad * 16) ^ swz));
        s8bf b3 = *(const s8bf*)(tb + ((192 + quad * 16) ^ swz));
        float2 cj = ucc[ct * 16 + l16];   // (u_col, w_col)

        f32x4 acc[2] = {{0.f,0.f,0.f,0.f}, {0.f,0.f,0.f,0.f}};
        acc[0] = MFMA16(a[0][0], b0, acc[0]);
        acc[0] = MFMA16(a[0][1], b1, acc[0]);
        acc[0] = MFMA16(a[0][2], b2, acc[0]);
        acc[0] = MFMA16(a[0][3], b3, acc[0]);
        acc[1] = MFMA16(a[1][0], b0, acc[1]);
        acc[1] = MFMA16(a[1][1], b1, acc[1]);
        acc[1] = MFMA16(a[1][2], b2, acc[1]);
        acc[1] = MFMA16(a[1][3], b3, acc[1]);

        float ctot = 0.0f, cdif = 0.0f;
        #pragma unroll
        for (int t = 0; t < 2; ++t)
            #pragma unroll
            for (int r = 0; r < 4; ++r) {
                float bias = fmaf(wr[t][r] * cj.y, 5e29f, -5e29f);
                float e = __builtin_amdgcn_exp2f(fmaf(acc[t][r], TEMP_SCALE, bias));
                rtot[t][r] += e;
                rdif[t][r] = fmaf(cj.x, e, rdif[t][r]);
                ctot += e;
                cdif = fmaf(ur[t][r], e, cdif);
            }

        // col-side: reduce over the 4 quads (rows), one slot per (wave, col)
        ctot += __shfl_xor(ctot, 16); cdif += __shfl_xor(cdif, 16);
        ctot += __shfl_xor(ctot, 32); cdif += __shfl_xor(cdif, 32);
        if (quad == 0) colbuf[wave][ct * 16 + l16] = make_float2(ctot, cdif);
    }
    __syncthreads();   // colbuf complete

    // ---- col-side combine (symmetric contribution), off-diag only ----
    if (offdiag && threadIdx.x < 128) {
        float2 c0 = colbuf[0][threadIdx.x], c1 = colbuf[1][threadIdx.x];
        float2 c2 = colbuf[2][threadIdx.x], c3 = colbuf[3][threadIdx.x];
        atomicAdd(&tot[colBase + threadIdx.x], (c0.x + c1.x) + (c2.x + c3.x));
        atomicAdd(&dif[colBase + threadIdx.x], (c0.y + c1.y) + (c2.y + c3.y));
    }

    // ---- row-side: reduce over the 16 column-lanes, atomics per row ----
    #pragma unroll
    for (int t = 0; t < 2; ++t)
        #pragma unroll
        for (int r = 0; r < 4; ++r) {
            float tv = rtot[t][r], dv = rdif[t][r];
            tv += __shfl_xor(tv, 1); dv += __shfl_xor(dv, 1);
            tv += __shfl_xor(tv, 2); dv += __shfl_xor(dv, 2);
            tv += __shfl_xor(tv, 4); dv += __shfl_xor(dv, 4);
            tv += __shfl_xor(tv, 8); dv += __shfl_xor(dv, 8);
            if (l16 == 0) {
                int row = rowBase + t * 16 + quad * 4 + r;
                atomicAdd(&tot[row], tv);
                atomicAdd(&dif[row], dv);
            }
        }
}

// ---------------- fin ----------------
__global__ __launch_bounds__(1024) void fin_kernel(
    const float* __restrict__ tot, const float* __restrict__ dif,
    const float* __restrict__ sd, const float2* __restrict__ uc,
    float* __restrict__ out, int B)
{
    __shared__ float ssum[16], scnt[16];
    float sum = 0.0f, cnt = 0.0f;
    for (int i = threadIdx.x; i < B; i += 1024) {
        float u = uc[i].x;
        float P = tot[i];
        float Q = u * dif[i];
        // pos (excl. diag) = (P+Q)/2 - exp2(S*selfdot); invalid rows have
        // P=Q=0 -> pos < 0 -> skipped (matches ref's empty-pos/neg skip)
        float pos = 0.5f * (P + Q) - __builtin_amdgcn_exp2f(TEMP_SCALE * sd[i]);
        float neg = 0.5f * (P - Q);
        if (pos > 0.0f && neg > 0.0f) {
            sum += logf((pos + neg + 1e-8f) / pos);
            cnt += 1.0f;
        }
    }
    #pragma unroll
    for (int m = 32; m; m >>= 1) {
        sum += __shfl_xor(sum, m);
        cnt += __shfl_xor(cnt, m);
    }
    int wave = threadIdx.x >> 6, lane = threadIdx.x & 63;
    if (lane == 0) { ssum[wave] = sum; scnt[wave] = cnt; }
    __syncthreads();
    if (threadIdx.x == 0) {
        float S = 0.0f, C = 0.0f;
        #pragma unroll
        for (int w = 0; w < 16; ++w) { S += ssum[w]; C += scnt[w]; }
        out[0] = (C > 0.0f) ? S / fmaxf(C, 1.0f) : 0.0f;
    }
}

extern "C" void kernel_launch(void* const* d_in, const int* in_sizes, int n_in,
                              void* d_out, int out_size, void* d_ws, size_t ws_size,
                              hipStream_t stream) {
    const float* emb    = (const float*)d_in[0];
    const int*   labels = (const int*)d_in[1];
    const float* conf   = (const float*)d_in[2];
    float* out = (float*)d_out;
    int B = in_sizes[1];   // 8192

    char* ws = (char*)d_ws;
    size_t off = 0;
    short*  Eb  = (short*)(ws + off);  off += (size_t)B * DDIM * 2;
    float2* ucp = (float2*)(ws + off); off += (size_t)B * 8;
    float*  sd  = (float*)(ws + off);  off += (size_t)B * 4;
    float*  tot = (float*)(ws + off);  off += (size_t)B * 4;
    float*  dif = (float*)(ws + off);  off += (size_t)B * 4;

    prep_kernel<<<B / 4, 256, 0, stream>>>(emb, labels, conf, Eb, ucp, sd, tot, dif, B);

    int NT = B / 128;                    // 64 tiles per side
    int nblk = NT * (NT + 1) / 2;        // 2080 upper-triangle tile-pairs
    sim_kernel<<<nblk, 256, 0, stream>>>(Eb, ucp, tot, dif, NT);

    fin_kernel<<<1, 1024, 0, stream>>>(tot, dif, sd, ucp, out, B);
}

// Round 7
// 105.048 us; speedup vs baseline: 1.0208x; 1.0208x over previous
//
#include <hip/hip_runtime.h>
#include <cstddef>

// InfoNCE loss, B=8192, D=128.
// prep: normalize + bf16(sqrt(S)*e) cast + (label u, conf-sign w) + self-dot
// sim:  triangle-symmetric bf16 MFMA E.E^T, 4 tile-pairs per block (chunked),
//       double-buffered DMA staging (r5-verified swizzle), row+col masked sums.
//       sqrt(S) folded into BOTH operands (symmetric, kills per-elem scale-fma).
//       amdgpu_waves_per_eu(2,2): allocator pins 128 VGPRs (r4 evidence); static
//       demand ~110 fits -> no spill (r6: launch_bounds(256,2) landed 76 -> spill).
// fin:  per-row loss from (tot, dif), mean over valid rows

#define DDIM 128
#define SQRT_TS 3.7982825f   // sqrt((1/0.1) * log2(e)); applied to both operands
#define CHUNK 4              // tile-pairs per block; 2080/4 = 520 blocks

typedef short s8bf __attribute__((ext_vector_type(8)));   // 8 bf16 (4 VGPRs)
typedef float f32x4 __attribute__((ext_vector_type(4)));

typedef __attribute__((address_space(1))) void gas_void;
typedef __attribute__((address_space(3))) void las_void;

__device__ __forceinline__ void gload_lds16(const void* g, void* l) {
    __builtin_amdgcn_global_load_lds((gas_void*)g, (las_void*)l, 16, 0, 0);
}

__device__ __forceinline__ unsigned short f2bf(float f) {
    unsigned int u = __float_as_uint(f);
    u += 0x7fffu + ((u >> 16) & 1u);
    return (unsigned short)(u >> 16);
}
__device__ __forceinline__ float bf2f(unsigned short h) {
    return __uint_as_float(((unsigned int)h) << 16);
}

// ---------------- prep: one wave per row ----------------
__global__ __launch_bounds__(256) void prep_kernel(
    const float* __restrict__ emb, const int* __restrict__ labels,
    const float* __restrict__ conf,
    short* __restrict__ Eb,    // bf16(sqrt(S) * e) — the ONLY embedding array
    float2* __restrict__ uc,   // (label +-1, conf-sign w)
    float* __restrict__ sd,    // self-dot of scaled bf16 values = S*|e|^2 (log2 domain)
    float* __restrict__ tot, float* __restrict__ dif, int B)
{
    int wave = threadIdx.x >> 6;
    int lane = threadIdx.x & 63;
    int row  = blockIdx.x * 4 + wave;
    if (row >= B) return;

    float2 x = ((const float2*)(emb + (size_t)row * DDIM))[lane];
    float ss = x.x * x.x + x.y * x.y;
    #pragma unroll
    for (int m = 32; m; m >>= 1) ss += __shfl_xor(ss, m);
    float inv = SQRT_TS / fmaxf(sqrtf(ss), 1e-12f);

    unsigned short eb0 = f2bf(x.x * inv), eb1 = f2bf(x.y * inv);
    *(ushort2*)(Eb + (size_t)row * DDIM + lane * 2) = make_ushort2(eb0, eb1);

    float b0 = bf2f(eb0), b1 = bf2f(eb1);
    float p = b0 * b0 + b1 * b1;
    #pragma unroll
    for (int m = 32; m; m >>= 1) p += __shfl_xor(p, m);

    if (lane == 0) {
        sd[row] = p;
        float l = labels[row] ? 1.0f : -1.0f;
        float c = conf[row];
        float w = (c > 0.0f) ? 1.0f : ((c < 0.0f) ? -1.0f : 0.0f);
        uc[row] = make_float2(l, w);
        tot[row] = 0.0f;
        dif[row] = 0.0f;
    }
}

// ---------------- sim ----------------
// Upper-triangle tile-pairs (bi<=bj), lexicographic, CHUNK consecutive per block.
// Per block: A-frags/row-sums persist across the chunk (bi rarely changes);
// col tiles double-buffer staged via swizzled gload_lds
// (LDS[L] = G[L ^ ((L>>8&7)<<4)], reads apply same XOR; r5/r6-verified).
// Per element: bias = fma(w_row, w_col*5e29, -5e29) (0 valid / <=-5e29 invalid);
// e = exp2(acc + bias); row: rtot+=e, rdif+=u_col*e; col (offdiag): ctot, cdif.
#define MFMA16(A, Bf, C) __builtin_amdgcn_mfma_f32_16x16x32_bf16((A), (Bf), (C), 0, 0, 0)

__device__ __forceinline__ void stage_tile(const short* __restrict__ Eb, int colBase,
                                           short* buf, int wave, int lane) {
    const char* gb = (const char*)Eb + (size_t)colBase * 256;
    #pragma unroll
    for (int i = 0; i < 8; ++i) {
        int L  = i * 4096 + wave * 1024 + lane * 16;
        int Ls = L ^ (((L >> 8) & 7) << 4);   // inverse-swizzled source
        gload_lds16(gb + Ls, (char*)buf + L);
    }
}

__global__ __launch_bounds__(256) __attribute__((amdgpu_waves_per_eu(2, 2)))
void sim_kernel(
    const short* __restrict__ Eb, const float2* __restrict__ uc,
    float* __restrict__ tot, float* __restrict__ dif, int NT)
{
    __shared__ short tile[2][128 * 128];     // 64 KB, swizzled, linear for gload_lds
    __shared__ float2 ucc[2][128];           // 2 KB col (u, w), double-buffered
    __shared__ float2 colbuf[2][4][128];     // 8 KB per-wave col partials, dbuf

    const int lane = threadIdx.x & 63;
    const int wave = threadIdx.x >> 6;
    const int l16  = lane & 15;
    const int quad = lane >> 4;
    const int swz  = (l16 & 7) << 4;

    // triangle decode of chunk start: C(i) = i*(M-i)/2, M = 2*NT+1
    const int M = 2 * NT + 1;
    int bid = (int)blockIdx.x * CHUNK;
    int bi = (int)((M - sqrtf((float)(M * M - 8 * bid))) * 0.5f);
    while (bi > 0 && bi * (M - bi) / 2 > bid) --bi;
    while ((bi + 1) * (M - bi - 1) / 2 <= bid) ++bi;
    int bj = bi + (bid - bi * (M - bi) / 2);

    s8bf a[2][4];
    float ur[2][4], wr[2][4], rtot[2][4], rdif[2][4];

    #define LOAD_ROWPANEL(bi_) do { \
        int rb = (bi_) * 128 + wave * 32; \
        _Pragma("unroll") for (int t = 0; t < 2; ++t) \
            _Pragma("unroll") for (int k2 = 0; k2 < 4; ++k2) \
                a[t][k2] = *(const s8bf*)(Eb + (size_t)(rb + t * 16 + l16) * DDIM + k2 * 32 + quad * 8); \
        _Pragma("unroll") for (int t = 0; t < 2; ++t) \
            _Pragma("unroll") for (int r = 0; r < 4; ++r) { \
                float2 v = uc[rb + t * 16 + quad * 4 + r]; \
                ur[t][r] = v.x; wr[t][r] = v.y; \
                rtot[t][r] = 0.0f; rdif[t][r] = 0.0f; } \
    } while (0)

    #define FLUSH_ROWS(bi_) do { \
        _Pragma("unroll") for (int t = 0; t < 2; ++t) \
            _Pragma("unroll") for (int r = 0; r < 4; ++r) { \
                float tv = rtot[t][r], dv = rdif[t][r]; \
                tv += __shfl_xor(tv, 1); dv += __shfl_xor(dv, 1); \
                tv += __shfl_xor(tv, 2); dv += __shfl_xor(dv, 2); \
                tv += __shfl_xor(tv, 4); dv += __shfl_xor(dv, 4); \
                tv += __shfl_xor(tv, 8); dv += __shfl_xor(dv, 8); \
                if (l16 == 0) { \
                    int row = (bi_) * 128 + wave * 32 + t * 16 + quad * 4 + r; \
                    atomicAdd(&tot[row], tv); \
                    atomicAdd(&dif[row], dv); } } \
    } while (0)

    // prologue: stage tile 0, load row panel (overlaps DMA), barrier drains DMA
    stage_tile(Eb, bj * 128, &tile[0][0], wave, lane);
    if (threadIdx.x < 128) ucc[0][threadIdx.x] = uc[bj * 128 + threadIdx.x];
    LOAD_ROWPANEL(bi);
    int cur_bi = bi;
    __syncthreads();

    int cbi = bi, cbj = bj;
    #pragma unroll 1
    for (int k = 0; k < CHUNK; ++k) {
        // next tile indices; issue its DMA now (flies under this tile's compute)
        int nbi = cbi, nbj = cbj + 1;
        if (nbj == NT) { ++nbi; nbj = nbi; }
        if (k + 1 < CHUNK) {
            stage_tile(Eb, nbj * 128, &tile[(k + 1) & 1][0], wave, lane);
            if (threadIdx.x < 128) ucc[(k + 1) & 1][threadIdx.x] = uc[nbj * 128 + threadIdx.x];
        }
        __builtin_amdgcn_sched_barrier(0);

        if (cbi != cur_bi) {   // rare: row panel changed (<= 63 times total)
            FLUSH_ROWS(cur_bi);
            LOAD_ROWPANEL(cbi);
            cur_bi = cbi;
        }

        const char* tb0 = (const char*)&tile[k & 1][0];
        #pragma unroll
        for (int ct = 0; ct < 8; ++ct) {
            const char* tb = tb0 + (ct * 16 + l16) * 256;
            s8bf b0 = *(const s8bf*)(tb + ((  0 + quad * 16) ^ swz));
            s8bf b1 = *(const s8bf*)(tb + (( 64 + quad * 16) ^ swz));
            s8bf b2 = *(const s8bf*)(tb + ((128 + quad * 16) ^ swz));
            s8bf b3 = *(const s8bf*)(tb + ((192 + quad * 16) ^ swz));
            float2 cj = ucc[k & 1][ct * 16 + l16];   // (u_col, w_col)
            float cby = cj.y * 5e29f;

            f32x4 acc[2] = {{0.f,0.f,0.f,0.f}, {0.f,0.f,0.f,0.f}};
            acc[0] = MFMA16(a[0][0], b0, acc[0]);
            acc[0] = MFMA16(a[0][1], b1, acc[0]);
            acc[0] = MFMA16(a[0][2], b2, acc[0]);
            acc[0] = MFMA16(a[0][3], b3, acc[0]);
            acc[1] = MFMA16(a[1][0], b0, acc[1]);
            acc[1] = MFMA16(a[1][1], b1, acc[1]);
            acc[1] = MFMA16(a[1][2], b2, acc[1]);
            acc[1] = MFMA16(a[1][3], b3, acc[1]);

            float ctot = 0.0f, cdif = 0.0f;
            #pragma unroll
            for (int t = 0; t < 2; ++t)
                #pragma unroll
                for (int r = 0; r < 4; ++r) {
                    float bias = fmaf(wr[t][r], cby, -5e29f);   // 0 valid, <=-5e29 not
                    float e = __builtin_amdgcn_exp2f(acc[t][r] + bias);
                    rtot[t][r] += e;
                    rdif[t][r] = fmaf(cj.x, e, rdif[t][r]);
                    ctot += e;
                    cdif = fmaf(ur[t][r], e, cdif);
                }

            // col-side: reduce over the 4 quads (rows), one slot per (wave, col)
            ctot += __shfl_xor(ctot, 16); cdif += __shfl_xor(cdif, 16);
            ctot += __shfl_xor(ctot, 32); cdif += __shfl_xor(cdif, 32);
            if (quad == 0) colbuf[k & 1][wave][ct * 16 + l16] = make_float2(ctot, cdif);
        }
        __syncthreads();   // closes read window on tile[k&1]; drains k+1 DMA; colbuf done

        // col-side combine (symmetric contribution), off-diag only; overlaps k+1
        if (cbi != cbj && threadIdx.x < 128) {
            float2 c0 = colbuf[k & 1][0][threadIdx.x], c1 = colbuf[k & 1][1][threadIdx.x];
            float2 c2 = colbuf[k & 1][2][threadIdx.x], c3 = colbuf[k & 1][3][threadIdx.x];
            atomicAdd(&tot[cbj * 128 + threadIdx.x], (c0.x + c1.x) + (c2.x + c3.x));
            atomicAdd(&dif[cbj * 128 + threadIdx.x], (c0.y + c1.y) + (c2.y + c3.y));
        }
        cbi = nbi; cbj = nbj;
    }
    FLUSH_ROWS(cur_bi);
}

// ---------------- fin ----------------
__global__ __launch_bounds__(1024) void fin_kernel(
    const float* __restrict__ tot, const float* __restrict__ dif,
    const float* __restrict__ sd, const float2* __restrict__ uc,
    float* __restrict__ out, int B)
{
    __shared__ float ssum[16], scnt[16];
    float sum = 0.0f, cnt = 0.0f;
    for (int i = threadIdx.x; i < B; i += 1024) {
        float u = uc[i].x;
        float P = tot[i];
        float Q = u * dif[i];
        // pos (excl. diag) = (P+Q)/2 - exp2(sd); invalid rows have P=Q=0 -> skipped
        float pos = 0.5f * (P + Q) - __builtin_amdgcn_exp2f(sd[i]);
        float neg = 0.5f * (P - Q);
        if (pos > 0.0f && neg > 0.0f) {
            sum += logf((pos + neg + 1e-8f) / pos);
            cnt += 1.0f;
        }
    }
    #pragma unroll
    for (int m = 32; m; m >>= 1) {
        sum += __shfl_xor(sum, m);
        cnt += __shfl_xor(cnt, m);
    }
    int wave = threadIdx.x >> 6, lane = threadIdx.x & 63;
    if (lane == 0) { ssum[wave] = sum; scnt[wave] = cnt; }
    __syncthreads();
    if (threadIdx.x == 0) {
        float S = 0.0f, C = 0.0f;
        #pragma unroll
        for (int w = 0; w < 16; ++w) { S += ssum[w]; C += scnt[w]; }
        out[0] = (C > 0.0f) ? S / fmaxf(C, 1.0f) : 0.0f;
    }
}

extern "C" void kernel_launch(void* const* d_in, const int* in_sizes, int n_in,
                              void* d_out, int out_size, void* d_ws, size_t ws_size,
                              hipStream_t stream) {
    const float* emb    = (const float*)d_in[0];
    const int*   labels = (const int*)d_in[1];
    const float* conf   = (const float*)d_in[2];
    float* out = (float*)d_out;
    int B = in_sizes[1];   // 8192

    char* ws = (char*)d_ws;
    size_t off = 0;
    short*  Eb  = (short*)(ws + off);  off += (size_t)B * DDIM * 2;
    float2* ucp = (float2*)(ws + off); off += (size_t)B * 8;
    float*  sd  = (float*)(ws + off);  off += (size_t)B * 4;
    float*  tot = (float*)(ws + off);  off += (size_t)B * 4;
    float*  dif = (float*)(ws + off);  off += (size_t)B * 4;

    prep_kernel<<<B / 4, 256, 0, stream>>>(emb, labels, conf, Eb, ucp, sd, tot, dif, B);

    int NT = B / 128;                    // 64 tiles per side
    int nblk = NT * (NT + 1) / 2 / CHUNK;  // 2080/4 = 520 blocks
    sim_kernel<<<nblk, 256, 0, stream>>>(Eb, ucp, tot, dif, NT);

    fin_kernel<<<1, 1024, 0, stream>>>(tot, dif, sd, ucp, out, B);
}